// Round 24
// baseline (66.777 us; speedup 1.0000x reference)
//
#include <hip/hip_runtime.h>
#include <hip/hip_bf16.h>
#include <math.h>

typedef __bf16 bf16_t;
typedef __bf16 bf16x4 __attribute__((ext_vector_type(4)));
typedef __bf16 bf16x8 __attribute__((ext_vector_type(8)));
typedef float  f32x4  __attribute__((ext_vector_type(4)));
typedef float  f32x16 __attribute__((ext_vector_type(16)));
typedef int    v2i    __attribute__((ext_vector_type(2)));

static constexpr int Bz = 8, Tt = 2048, Cc = 1024, Dd = 128;
static constexpr int Mm = Bz * Tt;     // 16384
static constexpr int NT128 = Tt / 128; // 16 q-blocks per batch

__device__ __forceinline__ bf16x8 lds_read8(const char* base, int byte) {
    return *(const bf16x8*)(base + byte);
}

__device__ __forceinline__ bf16x8 cvt8(float4 a, float4 b) {
    bf16x8 r;
    r[0] = (bf16_t)a.x; r[1] = (bf16_t)a.y; r[2] = (bf16_t)a.z; r[3] = (bf16_t)a.w;
    r[4] = (bf16_t)b.x; r[5] = (bf16_t)b.y; r[6] = (bf16_t)b.z; r[7] = (bf16_t)b.w;
    return r;
}

__device__ __forceinline__ unsigned cvtpk(float lo, float hi) {
    unsigned r;
    asm("v_cvt_pk_bf16_f32 %0, %1, %2" : "=v"(r) : "v"(lo), "v"(hi));
    return r;
}

typedef const __attribute__((address_space(1))) unsigned int* as1_u32p;
typedef __attribute__((address_space(3))) unsigned int* as3_u32p;

__device__ __forceinline__ void gload_lds16(const bf16_t* g, bf16_t* l) {
    __builtin_amdgcn_global_load_lds((as1_u32p)(const void*)g, (as3_u32p)(void*)l, 16, 0, 0);
}

// ---------------- W f32 -> bf16, packed per (ktile, colgroup-of-128) tile ----
// (n 0..383, k 0..1023): ktile=k>>6, kk=(k>>5)&1, hi=(k>>3)&3, e=k&7,
// ng=n>>4 (0..23), cg=ng>>3 (0..2), ngl=ng&7, lo=n&15.
// Each (ktile,cg) tile is 16KB contiguous; each wave fragment 1KB contiguous.
__global__ __launch_bounds__(256) void wcvt_kernel(
    const float* __restrict__ Wq, const float* __restrict__ Wk,
    const float* __restrict__ Wv, bf16_t* __restrict__ Wp)
{
    int g = (blockIdx.x * 256 + threadIdx.x) * 4;
    int n = g >> 10;
    int k = g & 1023;
    int sel = n >> 7;
    const float* W = (sel == 0) ? Wq : (sel == 1) ? Wk : Wv;
    float4 f = *(const float4*)(W + (size_t)(n & 127) * 1024 + k);
    bf16x4 o; o[0] = (bf16_t)f.x; o[1] = (bf16_t)f.y; o[2] = (bf16_t)f.z; o[3] = (bf16_t)f.w;
    int ktile = k >> 6, kk = (k >> 5) & 1, hi = (k >> 3) & 3, e = k & 7;
    int ng = n >> 4, cg = ng >> 3, ngl = ng & 7, lo = n & 15;
    size_t addr = (size_t)(((((ktile * 3 + cg) * 8 + ngl) * 2 + kk) * 4 + hi) * 16 + lo) * 8 + e;
    *(bf16x4*)(Wp + addr) = o;
}

// ---------------- fused QKV projection: 3 col-groups, 3 blocks/CU ----------
// grid (256,3), 512 thr = 8 waves (2 row x 4 col groups of 32 cols).
// W (16KB/step, fragment-packed) via global_load_lds dbuf; x reg-staged bf16
// swizzled dbuf, issued one step early (r19). Counted vmcnt (T4): steady
// state 6 outstanding, vmcnt(4) drains exactly W(t). LDS 48KB -> 3 blocks/CU.
__global__ __launch_bounds__(512, 6) void qkv_fused(
    const float* __restrict__ x, const bf16_t* __restrict__ Wp,
    const float* __restrict__ bq, const float* __restrict__ bk, const float* __restrict__ bv,
    bf16_t* __restrict__ qo, bf16_t* __restrict__ ko, bf16_t* __restrict__ vTo)
{
    const int m0  = blockIdx.x * 64;
    const int cg  = blockIdx.y;          // 0..2, 128 cols each
    const int tid = threadIdx.x;
    const int lane = tid & 63;
    const int wv  = tid >> 6;
    const int wr  = wv >> 2;             // 0..1
    const int cw  = wv & 3;              // 0..3 (x32 cols)
    const int lo  = lane & 15;
    const int hi  = lane >> 4;

    __shared__ bf16_t Wl[2][8 * 2 * 512];    // 16KB per buf
    __shared__ bf16_t Xs[2][64 * 64];        // 8KB per buf (swizzled rows)

    f32x4 zero4 = {0.f, 0.f, 0.f, 0.f};
    f32x4 acc[2][2];
    #pragma unroll
    for (int i = 0; i < 2; i++)
        #pragma unroll
        for (int j = 0; j < 2; j++) acc[i][j] = zero4;

    const int xrow = tid >> 3;           // 0..63
    const int xcol = (tid & 7) * 8;      // 8 floats

    float4 fx[2];
    auto load_x = [&](int t) {
        const float4* s = (const float4*)(x + (size_t)(m0 + xrow) * Cc + t * 64 + xcol);
        fx[0] = s[0]; fx[1] = s[1];
    };
    auto write_x = [&](int buf) {
        int byte = (xrow * 128 + xcol * 2) ^ ((xrow & 7) << 4);
        *(bf16x8*)((char*)Xs[buf] + byte) = cvt8(fx[0], fx[1]);
    };
    auto stage_W = [&](int buf, int t) {
        const bf16_t* base = Wp + (size_t)(t * 3 + cg) * 8192;
        #pragma unroll
        for (int i = 0; i < 2; i++) {
            int c = i * 8 + wv;              // 1KB chunk 0..15
            gload_lds16(base + c * 512 + lane * 8, Wl[buf] + c * 512);
        }
    };
    auto compute = [&](int buf) {
        #pragma unroll
        for (int kk = 0; kk < 2; kk++) {
            int r0 = wr * 32 + lo;
            int r1 = wr * 32 + 16 + lo;
            bf16x8 af0 = lds_read8((char*)Xs[buf], (r0 * 128 + kk * 64 + hi * 16) ^ ((r0 & 7) << 4));
            bf16x8 af1 = lds_read8((char*)Xs[buf], (r1 * 128 + kk * 64 + hi * 16) ^ ((r1 & 7) << 4));
            #pragma unroll
            for (int j = 0; j < 2; j++) {
                bf16x8 bf = *(const bf16x8*)(Wl[buf] + ((cw * 2 + j) * 2 + kk) * 512 + lane * 8);
                acc[0][j] = __builtin_amdgcn_mfma_f32_16x16x32_bf16(af0, bf, acc[0][j], 0, 0, 0);
                acc[1][j] = __builtin_amdgcn_mfma_f32_16x16x32_bf16(af1, bf, acc[1][j], 0, 0, 0);
            }
        }
    };

    // prologue: x(0) -> Xs[0]; x(1) issued BEFORE the barrier; W(0) in flight
    load_x(0);
    stage_W(0, 0);
    write_x(0);                              // waits x(0) only
    load_x(1);                               // full-step cover for step 0's write_x
    asm volatile("s_waitcnt lgkmcnt(0)" ::: "memory");
    __builtin_amdgcn_s_barrier();
    // outstanding: W(0)x2, x(1)x2

    #pragma unroll 1
    for (int t = 0; t < 16; t++) {
        const int buf = t & 1;
        if (t < 15) {
            stage_W(buf ^ 1, t + 1);         // +2 -> W(t)2, x(t+1)2, W(t+1)2
            asm volatile("s_waitcnt vmcnt(4)" ::: "memory");   // drain W(t) only
        } else {
            asm volatile("s_waitcnt vmcnt(0)" ::: "memory");
        }
        __builtin_amdgcn_sched_barrier(0);
        compute(buf);
        if (t < 15) {
            write_x(buf ^ 1);                // x(t+1) issued a full step ago -> cheap wait
            if (t < 14) load_x(t + 2);       // issue next x before the barrier
            asm volatile("s_waitcnt lgkmcnt(0)" ::: "memory");
            __builtin_amdgcn_s_barrier();    // W(t+1), x(t+2) remain in flight
        }
    }

    #pragma unroll
    for (int j = 0; j < 2; j++) {
        int n = cg * 128 + cw * 32 + j * 16 + lo;
        int tsel = n >> 7, d = n & 127;      // tsel == cg (block-uniform)
        const float* bp = (tsel == 0) ? bq : (tsel == 1) ? bk : bv;
        float bb = bp[d];
        #pragma unroll
        for (int i = 0; i < 2; i++)
            #pragma unroll
            for (int r = 0; r < 4; r++) {
                int m = m0 + wr * 32 + i * 16 + hi * 4 + r;
                float v = acc[i][j][r] + bb;
                if (tsel == 0)      qo[(size_t)m * Dd + d] = (bf16_t)v;
                else if (tsel == 1) ko[(size_t)m * Dd + d] = (bf16_t)v;
                else                vTo[(size_t)d * Mm + m] = (bf16_t)v;
            }
    }
}

// ---------------- causal flash attention (KV-split partials, bf16 Opart) ----
__global__ __launch_bounds__(256, 2) void attn_kernel(
    const bf16_t* __restrict__ qi, const bf16_t* __restrict__ ki,
    const bf16_t* __restrict__ vTi,
    bf16_t* __restrict__ Opart, float* __restrict__ Mpart, float* __restrict__ Lpart,
    int nsplit)
{
    const int g   = blockIdx.x;
    const int per = nsplit * 8;
    const int qt  = (NT128 - 1) - g / per;
    const int rem = g % per;
    const int s   = rem >> 3;
    const int b   = rem & 7;
    const int nt  = 2 * qt + 2;
    const int t_lo = (s * nt) / nsplit;
    const int t_hi = ((s + 1) * nt) / nsplit;

    const int q0   = qt * 128;
    const int tid  = threadIdx.x;
    const int lane = tid & 63;
    const int w    = tid >> 6;
    const int rq   = lane & 31;
    const int dh   = lane >> 5;

    bf16_t* Ob = Opart + ((size_t)s * Mm + (size_t)b * Tt + q0) * Dd;
    float* Mb = Mpart + (size_t)s * Mm + (size_t)b * Tt + q0;
    float* Lb = Lpart + (size_t)s * Mm + (size_t)b * Tt + q0;

    if (t_lo >= t_hi) {  // empty split: zero the 128x128 bf16 partial (32KB)
        float4 z = {0.f, 0.f, 0.f, 0.f};
        #pragma unroll
        for (int i = 0; i < 8; i++)
            ((float4*)Ob)[i * 256 + tid] = z;
        if (tid < 128) { Mb[tid] = -INFINITY; Lb[tid] = 0.f; }
        return;
    }

    __shared__ __align__(16) char smem[65536];

    const float SCALE = 1.4426950408889634f / 32.0f;
    const int qg = q0 + w * 32 + rq;
    const int qwmax = q0 + w * 32 + 31;

    bf16x8 qf[8];
    {
        const bf16_t* qrow = qi + (size_t)(b * Tt + qg) * Dd;
        #pragma unroll
        for (int ks = 0; ks < 8; ks++)
            qf[ks] = *(const bf16x8*)(qrow + ks * 16 + dh * 8);
    }

    f32x16 accO[4];
    #pragma unroll
    for (int ds = 0; ds < 4; ds++)
        #pragma unroll
        for (int e = 0; e < 16; e++) accO[ds][e] = 0.f;
    float mrun = -INFINITY, lrun = 0.f;

    const int krow = tid >> 2;
    const int kcol = (tid & 3) * 32;
    const int vrow = tid >> 1;
    const int vcol = (tid & 1) * 32;

    bf16x8 kr[4], vr[4];
    auto load_kv = [&](int t) {
        const int kv0 = t * 64;
        const bf16_t* ksrc = ki + (size_t)(b * Tt + kv0 + krow) * Dd + kcol;
        #pragma unroll
        for (int i = 0; i < 4; i++) kr[i] = *(const bf16x8*)(ksrc + i * 8);
        const bf16_t* vsrc = vTi + (size_t)vrow * Mm + (b * Tt + kv0 + vcol);
        #pragma unroll
        for (int i = 0; i < 4; i++) vr[i] = *(const bf16x8*)(vsrc + i * 8);
    };
    auto write_kv = [&](int buf) {
        char* Ksb = smem + buf * 16384;
        char* Vsb = smem + 32768 + buf * 16384;
        #pragma unroll
        for (int i = 0; i < 4; i++) {
            int byte = (krow * 256 + (kcol + i * 8) * 2) ^ ((krow & 15) << 4);
            *(bf16x8*)(Ksb + byte) = kr[i];
        }
        const int vlr = vrow & 63;
        const int vlc = (vrow >> 6) * 64 + vcol;
        #pragma unroll
        for (int i = 0; i < 4; i++) {
            int byte = (vlr * 256 + (vlc + i * 8) * 2) ^ ((vlr & 15) << 4);
            *(bf16x8*)(Vsb + byte) = vr[i];
        }
    };

    load_kv(t_lo);
    write_kv(0);
    int buf = 0;

    for (int t = t_lo; t < t_hi; t++) {
        const int kv0 = t * 64;
        const bool more = (t + 1 < t_hi);
        __syncthreads();
        if (more) load_kv(t + 1);

        if (kv0 <= qwmax) {
            const char* Ksb = smem + buf * 16384;
            const char* Vsb = smem + 32768 + buf * 16384;

            f32x16 accS0, accS1;
            #pragma unroll
            for (int e = 0; e < 16; e++) { accS0[e] = 0.f; accS1[e] = 0.f; }
            #pragma unroll
            for (int ks = 0; ks < 8; ks++) {
                int colb = (ks * 16 + dh * 8) * 2;
                bf16x8 kf0 = lds_read8(Ksb, ((rq)      * 256 + colb) ^ ((rq & 15) << 4));
                bf16x8 kf1 = lds_read8(Ksb, ((32 + rq) * 256 + colb) ^ ((rq & 15) << 4));
                accS0 = __builtin_amdgcn_mfma_f32_32x32x16_bf16(kf0, qf[ks], accS0, 0, 0, 0);
                accS1 = __builtin_amdgcn_mfma_f32_32x32x16_bf16(kf1, qf[ks], accS1, 0, 0, 0);
            }

            float pl[32];
            #pragma unroll
            for (int e = 0; e < 16; e++) {
                pl[e]      = accS0[e] * SCALE;
                pl[16 + e] = accS1[e] * SCALE;
            }
            if (kv0 + 63 > qg) {
                #pragma unroll
                for (int e = 0; e < 16; e++) {
                    int kg = kv0 + 8 * (e >> 2) + (e & 3) + 4 * dh;
                    if (kg > qg)      pl[e]      = -INFINITY;
                    if (kg + 32 > qg) pl[16 + e] = -INFINITY;
                }
            }

            float mt = pl[0];
            #pragma unroll
            for (int e = 1; e < 32; e++) mt = fmaxf(mt, pl[e]);
            mt = fmaxf(mt, __shfl_xor(mt, 32, 64));
            float mnew = fmaxf(mrun, mt);
            float muse = (mnew == -INFINITY) ? 0.f : mnew;
            float alpha = exp2f(mrun - muse);
            mrun = mnew;
            float ps = 0.f;
            #pragma unroll
            for (int e = 0; e < 32; e++) {
                float pv = exp2f(pl[e] - muse);
                pl[e] = pv;
                ps += pv;
            }
            lrun = alpha * lrun + ps;
            #pragma unroll
            for (int ds = 0; ds < 4; ds++)
                #pragma unroll
                for (int e = 0; e < 16; e++) accO[ds][e] *= alpha;

            unsigned u0[8], u1[8];
            #pragma unroll
            for (int gg = 0; gg < 8; gg++) {
                u0[gg] = cvtpk(pl[4 * gg + 0], pl[4 * gg + 1]);
                u1[gg] = cvtpk(pl[4 * gg + 2], pl[4 * gg + 3]);
            }
            bf16x8 pa[4];
            #pragma unroll
            for (int ks = 0; ks < 4; ks++) {
                v2i rA = __builtin_amdgcn_permlane32_swap((int)u0[2 * ks], (int)u0[2 * ks + 1], false, false);
                v2i rB = __builtin_amdgcn_permlane32_swap((int)u1[2 * ks], (int)u1[2 * ks + 1], false, false);
                union { unsigned wd[4]; bf16x8 v; } pu;
                pu.wd[0] = (unsigned)rA[0];
                pu.wd[1] = (unsigned)rB[0];
                pu.wd[2] = (unsigned)rA[1];
                pu.wd[3] = (unsigned)rB[1];
                pa[ks] = pu.v;
            }

            #pragma unroll
            for (int ds = 0; ds < 4; ds++) {
                int row  = (ds & 1) * 32 + rq;
                int cb   = (ds >> 1) * 64;
                #pragma unroll
                for (int ks = 0; ks < 4; ks++) {
                    int colb = (cb + ks * 16 + dh * 8) * 2;
                    bf16x8 vf = lds_read8(Vsb, (row * 256 + colb) ^ ((row & 15) << 4));
                    accO[ds] = __builtin_amdgcn_mfma_f32_32x32x16_bf16(vf, pa[ks], accO[ds], 0, 0, 0);
                }
            }
        }

        __syncthreads();
        if (more) write_kv(buf ^ 1);
        buf ^= 1;
    }

    __syncthreads();

    lrun += __shfl_xor(lrun, 32, 64);

    // epilogue: transpose via per-wave slab, store partial as bf16
    char* slab = smem + w * 8192;
    #pragma unroll
    for (int half = 0; half < 2; half++) {
        #pragma unroll
        for (int dsl = 0; dsl < 2; dsl++) {
            #pragma unroll
            for (int e = 0; e < 16; e++) {
                int d = 8 * (e >> 2) + (e & 3) + 4 * dh + 32 * dsl;
                int byte = (rq * 256 + d * 4) ^ ((rq & 15) << 4);
                *(float*)(slab + byte) = accO[half * 2 + dsl][e];
            }
        }
        __builtin_amdgcn_s_waitcnt(0);
        #pragma unroll
        for (int i = 0; i < 8; i++) {
            int dd = 32 * dh + 4 * i;
            int byte = (rq * 256 + dd * 4) ^ ((rq & 15) << 4);
            float4 val = *(float4*)(slab + byte);
            bf16x4 o; o[0] = (bf16_t)val.x; o[1] = (bf16_t)val.y;
            o[2] = (bf16_t)val.z; o[3] = (bf16_t)val.w;
            *(bf16x4*)(Ob + (size_t)(w * 32 + rq) * Dd + half * 64 + dd) = o;
        }
        __builtin_amdgcn_s_waitcnt(0);
    }

    if (lane < 32) {
        Mb[w * 32 + rq] = mrun;
        Lb[w * 32 + rq] = lrun;
    }
}

// ---------------- split combine + normalize (bf16 partials in, f32 out) ----
__global__ __launch_bounds__(256) void combine_kernel(
    const bf16_t* __restrict__ Opart, const float* __restrict__ Mpart,
    const float* __restrict__ Lpart, float* __restrict__ out, int nsplit)
{
    int t   = blockIdx.x * 256 + threadIdx.x;
    int row = t >> 5;
    int dq  = (t & 31) << 2;
    float M = -INFINITY;
    for (int s = 0; s < nsplit; s++)
        M = fmaxf(M, Mpart[(size_t)s * Mm + row]);
    float L = 0.f;
    float o0 = 0.f, o1 = 0.f, o2 = 0.f, o3 = 0.f;
    for (int s = 0; s < nsplit; s++) {
        float ms = Mpart[(size_t)s * Mm + row];
        float ws = (ms == -INFINITY) ? 0.f : exp2f(ms - M);
        L += ws * Lpart[(size_t)s * Mm + row];
        bf16x4 p = *(const bf16x4*)(Opart + ((size_t)s * Mm + row) * Dd + dq);
        o0 += ws * (float)p[0]; o1 += ws * (float)p[1];
        o2 += ws * (float)p[2]; o3 += ws * (float)p[3];
    }
    float inv = 1.0f / L;
    float4 r; r.x = o0 * inv; r.y = o1 * inv; r.z = o2 * inv; r.w = o3 * inv;
    *(float4*)(out + (size_t)row * Dd + dq) = r;
}

extern "C" void kernel_launch(void* const* d_in, const int* in_sizes, int n_in,
                              void* d_out, int out_size, void* d_ws, size_t ws_size,
                              hipStream_t stream)
{
    const float* x  = (const float*)d_in[0];
    const float* Wq = (const float*)d_in[1];
    const float* bq = (const float*)d_in[2];
    const float* Wk = (const float*)d_in[3];
    const float* bk = (const float*)d_in[4];
    const float* Wv = (const float*)d_in[5];
    const float* bv = (const float*)d_in[6];
    float* out = (float*)d_out;

    bf16_t* qb = (bf16_t*)d_ws;                 // [M][D] bf16
    bf16_t* kb = qb + (size_t)Mm * Dd;          // [M][D] bf16
    bf16_t* vT = kb + (size_t)Mm * Dd;          // [D][M] bf16
    bf16_t* Wp = vT + (size_t)Mm * Dd;          // packed [384*1024] bf16
    char* p = (char*)(Wp + (size_t)384 * Cc);

    auto need = [&](int ns) {
        return (size_t)3 * Mm * Dd * 2 + (size_t)384 * Cc * 2
             + (size_t)ns * Mm * Dd * 2 + (size_t)ns * Mm * 8;
    };
    int nsplit = 4;
    while (nsplit > 1 && need(nsplit) > ws_size) nsplit >>= 1;

    bf16_t* Opart = (bf16_t*)p;                                   // [ns][M][D] bf16
    float* Mpart = (float*)(p + (size_t)nsplit * Mm * Dd * 2);    // [ns][M]
    float* Lpart = Mpart + (size_t)nsplit * Mm;                   // [ns][M]

    wcvt_kernel<<<dim3(384), 256, 0, stream>>>(Wq, Wk, Wv, Wp);
    qkv_fused<<<dim3(256, 3), 512, 0, stream>>>(x, Wp, bq, bk, bv, qb, kb, vT);
    attn_kernel<<<dim3(NT128 * nsplit * Bz), 256, 0, stream>>>(qb, kb, vT, Opart, Mpart, Lpart, nsplit);
    combine_kernel<<<dim3(Mm * 32 / 256), 256, 0, stream>>>(Opart, Mpart, Lpart, out, nsplit);
}

// Round 25
// 64.314 us; speedup vs baseline: 1.0383x; 1.0383x over previous
//
#include <hip/hip_runtime.h>
#include <hip/hip_bf16.h>
#include <math.h>

typedef __bf16 bf16_t;
typedef __bf16 bf16x4 __attribute__((ext_vector_type(4)));
typedef __bf16 bf16x8 __attribute__((ext_vector_type(8)));
typedef float  f32x4  __attribute__((ext_vector_type(4)));
typedef float  f32x16 __attribute__((ext_vector_type(16)));
typedef int    v2i    __attribute__((ext_vector_type(2)));

static constexpr int Bz = 8, Tt = 2048, Cc = 1024, Dd = 128;
static constexpr int Mm = Bz * Tt;     // 16384
static constexpr int NT128 = Tt / 128; // 16 q-blocks per batch

__device__ __forceinline__ bf16x8 lds_read8(const char* base, int byte) {
    return *(const bf16x8*)(base + byte);
}

__device__ __forceinline__ bf16x8 cvt8(float4 a, float4 b) {
    bf16x8 r;
    r[0] = (bf16_t)a.x; r[1] = (bf16_t)a.y; r[2] = (bf16_t)a.z; r[3] = (bf16_t)a.w;
    r[4] = (bf16_t)b.x; r[5] = (bf16_t)b.y; r[6] = (bf16_t)b.z; r[7] = (bf16_t)b.w;
    return r;
}

__device__ __forceinline__ unsigned cvtpk(float lo, float hi) {
    unsigned r;
    asm("v_cvt_pk_bf16_f32 %0, %1, %2" : "=v"(r) : "v"(lo), "v"(hi));
    return r;
}

typedef const __attribute__((address_space(1))) unsigned int* as1_u32p;
typedef __attribute__((address_space(3))) unsigned int* as3_u32p;

__device__ __forceinline__ void gload_lds16(const bf16_t* g, bf16_t* l) {
    __builtin_amdgcn_global_load_lds((as1_u32p)(const void*)g, (as3_u32p)(void*)l, 16, 0, 0);
}

// ---------------- W f32 -> bf16, packed per (ktile, colgroup) tile ----------
__global__ __launch_bounds__(256) void wcvt_kernel(
    const float* __restrict__ Wq, const float* __restrict__ Wk,
    const float* __restrict__ Wv, bf16_t* __restrict__ Wp)
{
    int g = (blockIdx.x * 256 + threadIdx.x) * 4;
    int n = g >> 10;
    int k = g & 1023;
    int sel = n >> 7;
    const float* W = (sel == 0) ? Wq : (sel == 1) ? Wk : Wv;
    float4 f = *(const float4*)(W + (size_t)(n & 127) * 1024 + k);
    bf16x4 o; o[0] = (bf16_t)f.x; o[1] = (bf16_t)f.y; o[2] = (bf16_t)f.z; o[3] = (bf16_t)f.w;
    int ktile = k >> 6, kk = (k >> 5) & 1, hi = (k >> 3) & 3, e = k & 7;
    int ng = n >> 4, cg = ng / 12, ngl = ng % 12, lo = n & 15;
    size_t addr = (size_t)(((((ktile * 2 + cg) * 12 + ngl) * 2 + kk) * 4 + hi) * 16 + lo) * 8 + e;
    *(bf16x4*)(Wp + addr) = o;
}

// ---------------- fused QKV projection: r13 + early x-issue ----------------
// grid (256,2), 512 thr = 8 waves. W (24KB/step) via global_load_lds dbuf;
// x reg-staged bf16 swizzled dbuf. load_x(t+1) is issued BEFORE the end-of-
// step-(t-1) barrier, so write_x's implicit wait has a full step of cover.
// Counted vmcnt keeps W(t+1)/x(t+1) in flight across barriers (T4).
__global__ __launch_bounds__(512, 4) void qkv_fused(
    const float* __restrict__ x, const bf16_t* __restrict__ Wp,
    const float* __restrict__ bq, const float* __restrict__ bk, const float* __restrict__ bv,
    bf16_t* __restrict__ qo, bf16_t* __restrict__ ko, bf16_t* __restrict__ vTo)
{
    const int m0  = blockIdx.x * 64;
    const int cg  = blockIdx.y;
    const int tid = threadIdx.x;
    const int lane = tid & 63;
    const int wv  = tid >> 6;
    const int wr  = wv >> 2;             // 0..1
    const int cw  = wv & 3;              // 0..3
    const int lo  = lane & 15;
    const int hi  = lane >> 4;

    __shared__ bf16_t Wl[2][12 * 2 * 512];   // 24KB per buf
    __shared__ bf16_t Xs[2][64 * 64];        // 8KB per buf (swizzled rows)

    f32x4 zero4 = {0.f, 0.f, 0.f, 0.f};
    f32x4 acc[2][3];
    #pragma unroll
    for (int i = 0; i < 2; i++)
        #pragma unroll
        for (int j = 0; j < 3; j++) acc[i][j] = zero4;

    const int xrow = tid >> 3;           // 0..63
    const int xcol = (tid & 7) * 8;      // 8 floats

    float4 fx[2];
    auto load_x = [&](int t) {
        const float4* s = (const float4*)(x + (size_t)(m0 + xrow) * Cc + t * 64 + xcol);
        fx[0] = s[0]; fx[1] = s[1];
    };
    auto write_x = [&](int buf) {
        int byte = (xrow * 128 + xcol * 2) ^ ((xrow & 7) << 4);
        *(bf16x8*)((char*)Xs[buf] + byte) = cvt8(fx[0], fx[1]);
    };
    auto stage_W = [&](int buf, int t) {
        const bf16_t* base = Wp + (size_t)(t * 2 + cg) * 12288;
        #pragma unroll
        for (int i = 0; i < 3; i++) {
            int c = i * 8 + wv;              // 1KB chunk 0..23
            gload_lds16(base + c * 512 + lane * 8, Wl[buf] + c * 512);
        }
    };
    auto compute = [&](int buf) {
        #pragma unroll
        for (int kk = 0; kk < 2; kk++) {
            int r0 = wr * 32 + lo;
            int r1 = wr * 32 + 16 + lo;
            bf16x8 af0 = lds_read8((char*)Xs[buf], (r0 * 128 + kk * 64 + hi * 16) ^ ((r0 & 7) << 4));
            bf16x8 af1 = lds_read8((char*)Xs[buf], (r1 * 128 + kk * 64 + hi * 16) ^ ((r1 & 7) << 4));
            #pragma unroll
            for (int j = 0; j < 3; j++) {
                bf16x8 bf = *(const bf16x8*)(Wl[buf] + ((cw * 3 + j) * 2 + kk) * 512 + lane * 8);
                acc[0][j] = __builtin_amdgcn_mfma_f32_16x16x32_bf16(af0, bf, acc[0][j], 0, 0, 0);
                acc[1][j] = __builtin_amdgcn_mfma_f32_16x16x32_bf16(af1, bf, acc[1][j], 0, 0, 0);
            }
        }
    };

    // prologue: x(0) -> Xs[0]; x(1) issued BEFORE the barrier; W(0) in flight
    load_x(0);
    stage_W(0, 0);
    write_x(0);                              // waits x(0) only
    load_x(1);                               // full-step cover for step 0's write_x
    asm volatile("s_waitcnt lgkmcnt(0)" ::: "memory");
    __builtin_amdgcn_s_barrier();
    // outstanding: W(0)x3, x(1)x2

    #pragma unroll 1
    for (int t = 0; t < 16; t++) {
        const int buf = t & 1;
        if (t < 15) {
            stage_W(buf ^ 1, t + 1);         // +3 -> W(t)3, x(t+1)2, W(t+1)3
            asm volatile("s_waitcnt vmcnt(5)" ::: "memory");   // drain W(t) only
        } else {
            asm volatile("s_waitcnt vmcnt(0)" ::: "memory");
        }
        __builtin_amdgcn_sched_barrier(0);
        compute(buf);
        if (t < 15) {
            write_x(buf ^ 1);                // x(t+1) issued a full step ago -> cheap wait
            if (t < 14) load_x(t + 2);       // issue next x before the barrier
            asm volatile("s_waitcnt lgkmcnt(0)" ::: "memory");
            __builtin_amdgcn_s_barrier();    // W(t+1), x(t+2) remain in flight
        }
    }

    #pragma unroll
    for (int j = 0; j < 3; j++) {
        int n = cg * 192 + cw * 48 + j * 16 + lo;
        int tsel = n >> 7, d = n & 127;
        const float* bp = (tsel == 0) ? bq : (tsel == 1) ? bk : bv;
        float bb = bp[d];
        #pragma unroll
        for (int i = 0; i < 2; i++)
            #pragma unroll
            for (int r = 0; r < 4; r++) {
                int m = m0 + wr * 32 + i * 16 + hi * 4 + r;
                float v = acc[i][j][r] + bb;
                if (tsel == 0)      qo[(size_t)m * Dd + d] = (bf16_t)v;
                else if (tsel == 1) ko[(size_t)m * Dd + d] = (bf16_t)v;
                else                vTo[(size_t)d * Mm + m] = (bf16_t)v;
            }
    }
}

// ---------------- causal flash attention (KV-split partials, bf16 Opart) ----
__global__ __launch_bounds__(256, 2) void attn_kernel(
    const bf16_t* __restrict__ qi, const bf16_t* __restrict__ ki,
    const bf16_t* __restrict__ vTi,
    bf16_t* __restrict__ Opart, float* __restrict__ Mpart, float* __restrict__ Lpart,
    int nsplit)
{
    const int g   = blockIdx.x;
    const int per = nsplit * 8;
    const int qt  = (NT128 - 1) - g / per;
    const int rem = g % per;
    const int s   = rem >> 3;
    const int b   = rem & 7;
    const int nt  = 2 * qt + 2;
    const int t_lo = (s * nt) / nsplit;
    const int t_hi = ((s + 1) * nt) / nsplit;

    const int q0   = qt * 128;
    const int tid  = threadIdx.x;
    const int lane = tid & 63;
    const int w    = tid >> 6;
    const int rq   = lane & 31;
    const int dh   = lane >> 5;

    bf16_t* Ob = Opart + ((size_t)s * Mm + (size_t)b * Tt + q0) * Dd;
    float* Mb = Mpart + (size_t)s * Mm + (size_t)b * Tt + q0;
    float* Lb = Lpart + (size_t)s * Mm + (size_t)b * Tt + q0;

    if (t_lo >= t_hi) {  // empty split: zero the 128x128 bf16 partial (32KB)
        float4 z = {0.f, 0.f, 0.f, 0.f};
        #pragma unroll
        for (int i = 0; i < 8; i++)
            ((float4*)Ob)[i * 256 + tid] = z;
        if (tid < 128) { Mb[tid] = -INFINITY; Lb[tid] = 0.f; }
        return;
    }

    __shared__ __align__(16) char smem[65536];

    const float SCALE = 1.4426950408889634f / 32.0f;
    const int qg = q0 + w * 32 + rq;
    const int qwmax = q0 + w * 32 + 31;

    bf16x8 qf[8];
    {
        const bf16_t* qrow = qi + (size_t)(b * Tt + qg) * Dd;
        #pragma unroll
        for (int ks = 0; ks < 8; ks++)
            qf[ks] = *(const bf16x8*)(qrow + ks * 16 + dh * 8);
    }

    f32x16 accO[4];
    #pragma unroll
    for (int ds = 0; ds < 4; ds++)
        #pragma unroll
        for (int e = 0; e < 16; e++) accO[ds][e] = 0.f;
    float mrun = -INFINITY, lrun = 0.f;

    const int krow = tid >> 2;
    const int kcol = (tid & 3) * 32;
    const int vrow = tid >> 1;
    const int vcol = (tid & 1) * 32;

    bf16x8 kr[4], vr[4];
    auto load_kv = [&](int t) {
        const int kv0 = t * 64;
        const bf16_t* ksrc = ki + (size_t)(b * Tt + kv0 + krow) * Dd + kcol;
        #pragma unroll
        for (int i = 0; i < 4; i++) kr[i] = *(const bf16x8*)(ksrc + i * 8);
        const bf16_t* vsrc = vTi + (size_t)vrow * Mm + (b * Tt + kv0 + vcol);
        #pragma unroll
        for (int i = 0; i < 4; i++) vr[i] = *(const bf16x8*)(vsrc + i * 8);
    };
    auto write_kv = [&](int buf) {
        char* Ksb = smem + buf * 16384;
        char* Vsb = smem + 32768 + buf * 16384;
        #pragma unroll
        for (int i = 0; i < 4; i++) {
            int byte = (krow * 256 + (kcol + i * 8) * 2) ^ ((krow & 15) << 4);
            *(bf16x8*)(Ksb + byte) = kr[i];
        }
        const int vlr = vrow & 63;
        const int vlc = (vrow >> 6) * 64 + vcol;
        #pragma unroll
        for (int i = 0; i < 4; i++) {
            int byte = (vlr * 256 + (vlc + i * 8) * 2) ^ ((vlr & 15) << 4);
            *(bf16x8*)(Vsb + byte) = vr[i];
        }
    };

    load_kv(t_lo);
    write_kv(0);
    int buf = 0;

    for (int t = t_lo; t < t_hi; t++) {
        const int kv0 = t * 64;
        const bool more = (t + 1 < t_hi);
        __syncthreads();
        if (more) load_kv(t + 1);

        if (kv0 <= qwmax) {
            const char* Ksb = smem + buf * 16384;
            const char* Vsb = smem + 32768 + buf * 16384;

            f32x16 accS0, accS1;
            #pragma unroll
            for (int e = 0; e < 16; e++) { accS0[e] = 0.f; accS1[e] = 0.f; }
            #pragma unroll
            for (int ks = 0; ks < 8; ks++) {
                int colb = (ks * 16 + dh * 8) * 2;
                bf16x8 kf0 = lds_read8(Ksb, ((rq)      * 256 + colb) ^ ((rq & 15) << 4));
                bf16x8 kf1 = lds_read8(Ksb, ((32 + rq) * 256 + colb) ^ ((rq & 15) << 4));
                accS0 = __builtin_amdgcn_mfma_f32_32x32x16_bf16(kf0, qf[ks], accS0, 0, 0, 0);
                accS1 = __builtin_amdgcn_mfma_f32_32x32x16_bf16(kf1, qf[ks], accS1, 0, 0, 0);
            }

            float pl[32];
            #pragma unroll
            for (int e = 0; e < 16; e++) {
                pl[e]      = accS0[e] * SCALE;
                pl[16 + e] = accS1[e] * SCALE;
            }
            if (kv0 + 63 > qg) {
                #pragma unroll
                for (int e = 0; e < 16; e++) {
                    int kg = kv0 + 8 * (e >> 2) + (e & 3) + 4 * dh;
                    if (kg > qg)      pl[e]      = -INFINITY;
                    if (kg + 32 > qg) pl[16 + e] = -INFINITY;
                }
            }

            float mt = pl[0];
            #pragma unroll
            for (int e = 1; e < 32; e++) mt = fmaxf(mt, pl[e]);
            mt = fmaxf(mt, __shfl_xor(mt, 32, 64));
            float mnew = fmaxf(mrun, mt);
            float muse = (mnew == -INFINITY) ? 0.f : mnew;
            float alpha = exp2f(mrun - muse);
            mrun = mnew;
            float ps = 0.f;
            #pragma unroll
            for (int e = 0; e < 32; e++) {
                float pv = exp2f(pl[e] - muse);
                pl[e] = pv;
                ps += pv;
            }
            lrun = alpha * lrun + ps;
            #pragma unroll
            for (int ds = 0; ds < 4; ds++)
                #pragma unroll
                for (int e = 0; e < 16; e++) accO[ds][e] *= alpha;

            unsigned u0[8], u1[8];
            #pragma unroll
            for (int gg = 0; gg < 8; gg++) {
                u0[gg] = cvtpk(pl[4 * gg + 0], pl[4 * gg + 1]);
                u1[gg] = cvtpk(pl[4 * gg + 2], pl[4 * gg + 3]);
            }
            bf16x8 pa[4];
            #pragma unroll
            for (int ks = 0; ks < 4; ks++) {
                v2i rA = __builtin_amdgcn_permlane32_swap((int)u0[2 * ks], (int)u0[2 * ks + 1], false, false);
                v2i rB = __builtin_amdgcn_permlane32_swap((int)u1[2 * ks], (int)u1[2 * ks + 1], false, false);
                union { unsigned wd[4]; bf16x8 v; } pu;
                pu.wd[0] = (unsigned)rA[0];
                pu.wd[1] = (unsigned)rB[0];
                pu.wd[2] = (unsigned)rA[1];
                pu.wd[3] = (unsigned)rB[1];
                pa[ks] = pu.v;
            }

            #pragma unroll
            for (int ds = 0; ds < 4; ds++) {
                int row  = (ds & 1) * 32 + rq;
                int cb   = (ds >> 1) * 64;
                #pragma unroll
                for (int ks = 0; ks < 4; ks++) {
                    int colb = (cb + ks * 16 + dh * 8) * 2;
                    bf16x8 vf = lds_read8(Vsb, (row * 256 + colb) ^ ((row & 15) << 4));
                    accO[ds] = __builtin_amdgcn_mfma_f32_32x32x16_bf16(vf, pa[ks], accO[ds], 0, 0, 0);
                }
            }
        }

        __syncthreads();
        if (more) write_kv(buf ^ 1);
        buf ^= 1;
    }

    __syncthreads();

    lrun += __shfl_xor(lrun, 32, 64);

    // epilogue: transpose via per-wave slab, store partial as bf16
    char* slab = smem + w * 8192;
    #pragma unroll
    for (int half = 0; half < 2; half++) {
        #pragma unroll
        for (int dsl = 0; dsl < 2; dsl++) {
            #pragma unroll
            for (int e = 0; e < 16; e++) {
                int d = 8 * (e >> 2) + (e & 3) + 4 * dh + 32 * dsl;
                int byte = (rq * 256 + d * 4) ^ ((rq & 15) << 4);
                *(float*)(slab + byte) = accO[half * 2 + dsl][e];
            }
        }
        __builtin_amdgcn_s_waitcnt(0);
        #pragma unroll
        for (int i = 0; i < 8; i++) {
            int dd = 32 * dh + 4 * i;
            int byte = (rq * 256 + dd * 4) ^ ((rq & 15) << 4);
            float4 val = *(float4*)(slab + byte);
            bf16x4 o; o[0] = (bf16_t)val.x; o[1] = (bf16_t)val.y;
            o[2] = (bf16_t)val.z; o[3] = (bf16_t)val.w;
            *(bf16x4*)(Ob + (size_t)(w * 32 + rq) * Dd + half * 64 + dd) = o;
        }
        __builtin_amdgcn_s_waitcnt(0);
    }

    if (lane < 32) {
        Mb[w * 32 + rq] = mrun;
        Lb[w * 32 + rq] = lrun;
    }
}

// ---------------- split combine + normalize (bf16 partials in, f32 out) ----
__global__ __launch_bounds__(256) void combine_kernel(
    const bf16_t* __restrict__ Opart, const float* __restrict__ Mpart,
    const float* __restrict__ Lpart, float* __restrict__ out, int nsplit)
{
    int t   = blockIdx.x * 256 + threadIdx.x;
    int row = t >> 5;
    int dq  = (t & 31) << 2;
    float M = -INFINITY;
    for (int s = 0; s < nsplit; s++)
        M = fmaxf(M, Mpart[(size_t)s * Mm + row]);
    float L = 0.f;
    float o0 = 0.f, o1 = 0.f, o2 = 0.f, o3 = 0.f;
    for (int s = 0; s < nsplit; s++) {
        float ms = Mpart[(size_t)s * Mm + row];
        float ws = (ms == -INFINITY) ? 0.f : exp2f(ms - M);
        L += ws * Lpart[(size_t)s * Mm + row];
        bf16x4 p = *(const bf16x4*)(Opart + ((size_t)s * Mm + row) * Dd + dq);
        o0 += ws * (float)p[0]; o1 += ws * (float)p[1];
        o2 += ws * (float)p[2]; o3 += ws * (float)p[3];
    }
    float inv = 1.0f / L;
    float4 r; r.x = o0 * inv; r.y = o1 * inv; r.z = o2 * inv; r.w = o3 * inv;
    *(float4*)(out + (size_t)row * Dd + dq) = r;
}

extern "C" void kernel_launch(void* const* d_in, const int* in_sizes, int n_in,
                              void* d_out, int out_size, void* d_ws, size_t ws_size,
                              hipStream_t stream)
{
    const float* x  = (const float*)d_in[0];
    const float* Wq = (const float*)d_in[1];
    const float* bq = (const float*)d_in[2];
    const float* Wk = (const float*)d_in[3];
    const float* bk = (const float*)d_in[4];
    const float* Wv = (const float*)d_in[5];
    const float* bv = (const float*)d_in[6];
    float* out = (float*)d_out;

    bf16_t* qb = (bf16_t*)d_ws;                 // [M][D] bf16
    bf16_t* kb = qb + (size_t)Mm * Dd;          // [M][D] bf16
    bf16_t* vT = kb + (size_t)Mm * Dd;          // [D][M] bf16
    bf16_t* Wp = vT + (size_t)Mm * Dd;          // packed [384*1024] bf16
    char* p = (char*)(Wp + (size_t)384 * Cc);

    auto need = [&](int ns) {
        return (size_t)3 * Mm * Dd * 2 + (size_t)384 * Cc * 2
             + (size_t)ns * Mm * Dd * 2 + (size_t)ns * Mm * 8;
    };
    int nsplit = 4;
    while (nsplit > 1 && need(nsplit) > ws_size) nsplit >>= 1;

    bf16_t* Opart = (bf16_t*)p;                                   // [ns][M][D] bf16
    float* Mpart = (float*)(p + (size_t)nsplit * Mm * Dd * 2);    // [ns][M]
    float* Lpart = Mpart + (size_t)nsplit * Mm;                   // [ns][M]

    wcvt_kernel<<<dim3(384), 256, 0, stream>>>(Wq, Wk, Wv, Wp);
    qkv_fused<<<dim3(256, 2), 512, 0, stream>>>(x, Wp, bq, bk, bv, qb, kb, vT);
    attn_kernel<<<dim3(NT128 * nsplit * Bz), 256, 0, stream>>>(qb, kb, vT, Opart, Mpart, Lpart, nsplit);
    combine_kernel<<<dim3(Mm * 32 / 256), 256, 0, stream>>>(Opart, Mpart, Lpart, out, nsplit);
}